// Round 2
// baseline (114.684 us; speedup 1.0000x reference)
//
#include <hip/hip_runtime.h>

typedef __attribute__((ext_vector_type(4))) float f32x4;
typedef __attribute__((ext_vector_type(8))) short bf16x8;

static __device__ __forceinline__ unsigned short f2bf(float f) {
    union { float f; unsigned int u; } v; v.f = f;
    unsigned int u = v.u;
    u += 0x7fffu + ((u >> 16) & 1u);   // round-to-nearest-even
    return (unsigned short)(u >> 16);
}

// Load 8 consecutive fp32 and convert to an MFMA bf16x8 A-fragment register.
static __device__ __forceinline__ bf16x8 ld_cvt8(const float* __restrict__ p) {
    float4 f0 = *reinterpret_cast<const float4*>(p);
    float4 f1 = *reinterpret_cast<const float4*>(p + 4);
    union { unsigned short u[8]; bf16x8 v; } o;
    o.u[0] = f2bf(f0.x); o.u[1] = f2bf(f0.y);
    o.u[2] = f2bf(f0.z); o.u[3] = f2bf(f0.w);
    o.u[4] = f2bf(f1.x); o.u[5] = f2bf(f1.y);
    o.u[6] = f2bf(f1.z); o.u[7] = f2bf(f1.w);
    return o.v;
}

// prep: permute adj + W into MFMA fragment-order bf16 buffers (1.9 MB traffic).
// Fragment chunk = 16 (m|n) x 32 (k) tile stored as [lane][8] bf16 (1 KB),
// lane = ((k&31)>>3)*16 + (m&15), elem jj = k&7.
//   adjfrag chunk = k0g*32 + m0              (512 chunks)
//   wtfrag  chunk = k0g*16 + n0   (Wt[n][k]=W[k][n], 128 chunks)
__global__ __launch_bounds__(256) void prep(
    const float* __restrict__ adj, const float* __restrict__ W,
    unsigned short* __restrict__ af, unsigned short* __restrict__ wf)
{
    const int wave = threadIdx.x >> 6, lane = threadIdx.x & 63;
    const int l15 = lane & 15, quad = lane >> 4;
    const int c = blockIdx.x * 4 + wave;     // 0..639, wave-uniform

    float t[8];
    unsigned short* dst;
    if (c < 512) {
        int k0g = c >> 5, m0 = c & 31;
        const float* src = adj + ((size_t)(m0 * 16 + l15)) * 512 + k0g * 32 + quad * 8;
        float4 f0 = *reinterpret_cast<const float4*>(src);
        float4 f1 = *reinterpret_cast<const float4*>(src + 4);
        t[0]=f0.x; t[1]=f0.y; t[2]=f0.z; t[3]=f0.w;
        t[4]=f1.x; t[5]=f1.y; t[6]=f1.z; t[7]=f1.w;
        dst = af + (size_t)c * 512 + lane * 8;
    } else {
        int c3 = c - 512, k0g = c3 >> 4, n0 = c3 & 15;
        int k = k0g * 32 + quad * 8, n = n0 * 16 + l15;
#pragma unroll
        for (int jj = 0; jj < 8; jj++) t[jj] = W[(size_t)(k + jj) * 256 + n];
        dst = wf + (size_t)c3 * 512 + lane * 8;
    }
    union { unsigned short u[8]; uint4 q; } o;
#pragma unroll
    for (int jj = 0; jj < 8; jj++) o.u[jj] = f2bf(t[jj]);
    *reinterpret_cast<uint4*>(dst) = o.q;
}

// xw: h = x @ W.  512 blocks x 256 threads (4 waves).
// Block = 64 rows x 256 cols (wave w owns cols w*64..+64) -> x read EXACTLY
// once (the 4 waves load identical x fragments; L1 serves waves 2-4).
// Output hf in B-fragment order for `ab`:
//   hf chunk = (b*16 + k0g)*16 + n0, layout [lane'][8]:
//   lane' = ((j&31)>>3)*16 + (d&15), elem = j&7.
__global__ __launch_bounds__(256, 3) void xw(
    const float* __restrict__ x, const unsigned short* __restrict__ wf,
    unsigned short* __restrict__ hf)
{
    const int tid = threadIdx.x;
    const int lane = tid & 63, wave = tid >> 6;   // 0..3
    const int l15 = lane & 15, quad = lane >> 4;
    const int blk = blockIdx.x;                   // 0..511, 64 j-rows each
    const int b = blk >> 3, jg = blk & 7;         // batch, 64-row group in batch

    // x row = blk*64 + mi*16 + l15, col = k*32 + quad*8 .. +8
    const float* xbase = x + ((size_t)(blk * 64 + l15)) * 256 + quad * 8;
    // wf chunk = k0g*16 + (wave*4 + ni); k0g step = 16*512 = 8192 elems
    const unsigned short* wfp = wf + ((size_t)(wave * 4)) * 512 + lane * 8;

    f32x4 acc[4][4];
#pragma unroll
    for (int mi = 0; mi < 4; mi++)
#pragma unroll
        for (int ni = 0; ni < 4; ni++) acc[mi][ni] = (f32x4){0.f,0.f,0.f,0.f};

#pragma unroll
    for (int k = 0; k < 8; k++) {
        bf16x8 bw[4], a[4];
#pragma unroll
        for (int ni = 0; ni < 4; ni++)
            bw[ni] = *reinterpret_cast<const bf16x8*>(
                wfp + (size_t)k * 8192 + ni * 512);
#pragma unroll
        for (int mi = 0; mi < 4; mi++)
            a[mi] = ld_cvt8(xbase + (size_t)mi * 16 * 256 + k * 32);
#pragma unroll
        for (int mi = 0; mi < 4; mi++)
#pragma unroll
            for (int ni = 0; ni < 4; ni++)
                acc[mi][ni] = __builtin_amdgcn_mfma_f32_16x16x32_bf16(
                    a[mi], bw[ni], acc[mi][ni], 0, 0, 0);
    }

    // Epilogue: C-layout (j_loc = mi*16 + quad*4 + r, d = wave*64 + ni*16 + l15) ->
    // B-frag: k0g = jg*2 + (mi>>1), lane' = ((mi&1)*2 + (quad>>1))*16 + l15,
    // elem = (quad&1)*4 + r.  16 consecutive l15 lanes -> 128 B contiguous store.
#pragma unroll
    for (int mi = 0; mi < 4; mi++) {
        int k0g   = jg * 2 + (mi >> 1);
        int quadp = (mi & 1) * 2 + (quad >> 1);
#pragma unroll
        for (int ni = 0; ni < 4; ni++) {
            ushort4 p;
            p.x = f2bf(acc[mi][ni][0]); p.y = f2bf(acc[mi][ni][1]);
            p.z = f2bf(acc[mi][ni][2]); p.w = f2bf(acc[mi][ni][3]);
            *reinterpret_cast<ushort4*>(
                hf + (((size_t)b * 16 + k0g) * 16 + wave * 4 + ni) * 512
                   + (quadp * 16 + l15) * 8 + (quad & 1) * 4) = p;
        }
    }
}

// ab: out = adj @ h per batch.  512 blocks x 256 threads (4 waves).
// Block = 256 out-rows x 64 cols.  blk = s*64 + b (s = rh*4 + dq) so the two
// row-halves of (b,dq) land on the same XCD (delta wg = 256 == 0 mod 8);
// per-XCD L2 set: af 512 KB + 8 batches' hf = ~2.5 MB < 4 MB.
__global__ __launch_bounds__(256, 3) void ab(
    const unsigned short* __restrict__ af, const unsigned short* __restrict__ hf,
    float* __restrict__ out)
{
    const int tid = threadIdx.x;
    const int lane = tid & 63, wave = tid >> 6;   // 0..3
    const int l15 = lane & 15, quad = lane >> 4;
    const int blk = blockIdx.x;
    const int s = blk >> 6, b = blk & 63;
    const int rh = s >> 2, dq = s & 3;

    // af chunk = k*32 + m0, m0 = rh*16 + wave*4 + mi
    const unsigned short* afp = af + ((size_t)(rh * 16 + wave * 4)) * 512 + lane * 8;
    // hf chunk = b*256 + k*16 + (dq*4 + ni)
    const unsigned short* hfp = hf + (((size_t)b * 256 + dq * 4)) * 512 + lane * 8;

    f32x4 o[4][4];
#pragma unroll
    for (int mi = 0; mi < 4; mi++)
#pragma unroll
        for (int ni = 0; ni < 4; ni++) o[mi][ni] = (f32x4){0.f,0.f,0.f,0.f};

#pragma unroll
    for (int k = 0; k < 16; k++) {
        bf16x8 a2[4], hb[4];
#pragma unroll
        for (int mi = 0; mi < 4; mi++)
            a2[mi] = *reinterpret_cast<const bf16x8*>(
                afp + ((size_t)k * 32 + mi) * 512);
#pragma unroll
        for (int ni = 0; ni < 4; ni++)
            hb[ni] = *reinterpret_cast<const bf16x8*>(
                hfp + ((size_t)k * 16 + ni) * 512);
#pragma unroll
        for (int mi = 0; mi < 4; mi++)
#pragma unroll
            for (int ni = 0; ni < 4; ni++)
                o[mi][ni] = __builtin_amdgcn_mfma_f32_16x16x32_bf16(
                    a2[mi], hb[ni], o[mi][ni], 0, 0, 0);
    }

    // Store fp32: row i = b*512 + rh*256 + wave*64 + mi*16 + quad*4 + r,
    // col = dq*64 + ni*16 + l15
    float* ob = out + ((size_t)(b * 512 + rh * 256 + wave * 64)) * 256 + dq * 64;
#pragma unroll
    for (int mi = 0; mi < 4; mi++) {
        int i0 = mi * 16 + quad * 4;
#pragma unroll
        for (int ni = 0; ni < 4; ni++) {
            int d = ni * 16 + l15;
#pragma unroll
            for (int r = 0; r < 4; r++)
                ob[(size_t)(i0 + r) * 256 + d] = o[mi][ni][r];
        }
    }
}

extern "C" void kernel_launch(void* const* d_in, const int* in_sizes, int n_in,
                              void* d_out, int out_size, void* d_ws, size_t ws_size,
                              hipStream_t stream) {
    const float* x   = (const float*)d_in[0];
    // d_in[1] = batch ids (unused; block-contiguous layout by construction)
    const float* W   = (const float*)d_in[2];
    const float* Adj = (const float*)d_in[3];
    float* out = (float*)d_out;

    unsigned short* afrag = (unsigned short*)d_ws;    // 262144 elems (512 KB)
    unsigned short* wfrag = afrag + 262144;           // 65536 elems (128 KB)
    unsigned short* hfrag = wfrag + 65536;            // 8388608 elems (16 MB)

    prep<<<160, 256, 0, stream>>>(Adj, W, afrag, wfrag);
    xw<<<512, 256, 0, stream>>>(x, wfrag, hfrag);
    ab<<<512, 256, 0, stream>>>(afrag, hfrag, out);
}

// Round 3
// 104.041 us; speedup vs baseline: 1.1023x; 1.1023x over previous
//
#include <hip/hip_runtime.h>

typedef __attribute__((ext_vector_type(4))) float f32x4;
typedef __attribute__((ext_vector_type(8))) short bf16x8;

static __device__ __forceinline__ unsigned short f2bf(float f) {
    union { float f; unsigned int u; } v; v.f = f;
    unsigned int u = v.u;
    u += 0x7fffu + ((u >> 16) & 1u);   // round-to-nearest-even
    return (unsigned short)(u >> 16);
}

// prep: permute inputs into MFMA fragment-order bf16 buffers.
// Fragment chunk = 16 (m|n) x 32 (k) tile stored as [lane][8] bf16 (1 KB),
// lane = ((k&31)>>3)*16 + (m&15), elem jj = k&7.
//   xfrag  chunk = (b*8 + k0g)*32 + m0          (16384 chunks)
//   adjfrag chunk = k0g*32 + m0                 (512 chunks)
//   wtfrag chunk = k0g*16 + n0   (Wt[n][k]=W[k][n], 128 chunks)
__global__ __launch_bounds__(256) void prep(
    const float* __restrict__ x, const float* __restrict__ adj,
    const float* __restrict__ W,
    unsigned short* __restrict__ xf, unsigned short* __restrict__ af,
    unsigned short* __restrict__ wf)
{
    const int wave = threadIdx.x >> 6, lane = threadIdx.x & 63;
    const int l15 = lane & 15, quad = lane >> 4;
    const int c = blockIdx.x * 4 + wave;     // 0..17023, wave-uniform

    float t[8];
    unsigned short* dst;
    if (c < 16384) {
        int b = c >> 8, k0g = (c >> 5) & 7, m0 = c & 31;
        const float* src = x + ((size_t)(b * 512 + m0 * 16 + l15)) * 256 + k0g * 32 + quad * 8;
        float4 f0 = *reinterpret_cast<const float4*>(src);
        float4 f1 = *reinterpret_cast<const float4*>(src + 4);
        t[0]=f0.x; t[1]=f0.y; t[2]=f0.z; t[3]=f0.w;
        t[4]=f1.x; t[5]=f1.y; t[6]=f1.z; t[7]=f1.w;
        dst = xf + (size_t)c * 512 + lane * 8;
    } else if (c < 16896) {
        int c2 = c - 16384, k0g = c2 >> 5, m0 = c2 & 31;
        const float* src = adj + ((size_t)(m0 * 16 + l15)) * 512 + k0g * 32 + quad * 8;
        float4 f0 = *reinterpret_cast<const float4*>(src);
        float4 f1 = *reinterpret_cast<const float4*>(src + 4);
        t[0]=f0.x; t[1]=f0.y; t[2]=f0.z; t[3]=f0.w;
        t[4]=f1.x; t[5]=f1.y; t[6]=f1.z; t[7]=f1.w;
        dst = af + (size_t)c2 * 512 + lane * 8;
    } else {
        int c3 = c - 16896, k0g = c3 >> 4, n0 = c3 & 15;
        int k = k0g * 32 + quad * 8, n = n0 * 16 + l15;
#pragma unroll
        for (int jj = 0; jj < 8; jj++) t[jj] = W[(size_t)(k + jj) * 256 + n];
        dst = wf + (size_t)c3 * 512 + lane * 8;
    }
    union { unsigned short u[8]; uint4 q; } o;
#pragma unroll
    for (int jj = 0; jj < 8; jj++) o.u[jj] = f2bf(t[jj]);
    *reinterpret_cast<uint4*>(dst) = o.q;
}

// Fused: block = (batch b, 64-col d-slice dq), 512 threads (8 waves).
// Each wave owns 64 rows x 64 cols -> 4x4 MFMA tile, 16 MFMA per 8 global
// loads per k-step (2x the MFMA:load ratio of the 32-wide variant).
// Phase 1: h[j][64 d] = x_b @ W[:,slice] -> LDS (exact phase-2 B-frag order).
// Phase 2: out_b[:, slice] = adj @ h.  No barriers inside K-loops.
__global__ __launch_bounds__(512, 2) void fused(
    const unsigned short* __restrict__ xf,
    const unsigned short* __restrict__ wf,
    const unsigned short* __restrict__ af,
    float* __restrict__ out)
{
    // ht[k0g(16)][ni(4)][lane(64)][8] bf16 = 64 KiB
    __shared__ __align__(16) unsigned short ht[32768];

    const int tid  = threadIdx.x;
    const int lane = tid & 63, wave = tid >> 6;   // wave 0..7
    const int l15  = lane & 15, quad = lane >> 4;
    const int b    = blockIdx.x;   // 0..63 (fast -> same-batch blocks share an XCD)
    const int dq   = blockIdx.y;   // 0..3

    // Per-lane base pointers (element units). Strides:
    //   xf: k0g step 32*64*8 = 16384 elems, mi step 512 elems
    //   wf: k0g step 16*64*8 =  8192 elems, ni step 512 elems
    //   af: k0g step 32*64*8 = 16384 elems, mi step 512 elems
    const unsigned short* xfp = xf + ((size_t)(b * 8) * 32 + wave * 4) * 512 + lane * 8;
    const unsigned short* wfp = wf + ((size_t)(dq * 4)) * 512 + lane * 8;
    const unsigned short* afp = af + ((size_t)(wave * 4)) * 512 + lane * 8;

    // ---------------- Phase 1: K=256, 8 k-steps; wave owns 64 j-rows ----------------
    f32x4 acc[4][4];
#pragma unroll
    for (int mi = 0; mi < 4; mi++)
#pragma unroll
        for (int ni = 0; ni < 4; ni++) acc[mi][ni] = (f32x4){0.f,0.f,0.f,0.f};

#pragma unroll
    for (int k = 0; k < 8; k++) {
        bf16x8 bw[4], a[4];
#pragma unroll
        for (int ni = 0; ni < 4; ni++)
            bw[ni] = *reinterpret_cast<const bf16x8*>(
                wfp + (size_t)k * 8192 + ni * 512);
#pragma unroll
        for (int mi = 0; mi < 4; mi++)
            a[mi] = *reinterpret_cast<const bf16x8*>(
                xfp + (size_t)k * 16384 + mi * 512);
#pragma unroll
        for (int mi = 0; mi < 4; mi++)
#pragma unroll
            for (int ni = 0; ni < 4; ni++)
                acc[mi][ni] = __builtin_amdgcn_mfma_f32_16x16x32_bf16(
                    a[mi], bw[ni], acc[mi][ni], 0, 0, 0);
    }

    // Epilogue: C-layout (j = wave*64 + mi*16 + quad*4 + r, dl = ni*16 + l15) ->
    // B-frag storage: k0g2 = wave*2 + (mi>>1), lane' = ((mi&1)*2+(quad>>1))*16 + l15,
    // elem = (quad&1)*4 + r  (r contiguous -> 8 B ds_write, conflict-free).
#pragma unroll
    for (int mi = 0; mi < 4; mi++) {
        int k0g2  = wave * 2 + (mi >> 1);
        int quadp = (mi & 1) * 2 + (quad >> 1);
#pragma unroll
        for (int ni = 0; ni < 4; ni++) {
            ushort4 p;
            p.x = f2bf(acc[mi][ni][0]); p.y = f2bf(acc[mi][ni][1]);
            p.z = f2bf(acc[mi][ni][2]); p.w = f2bf(acc[mi][ni][3]);
            *reinterpret_cast<ushort4*>(
                ht + ((k0g2 * 4 + ni) * 64 + quadp * 16 + l15) * 8
                   + (quad & 1) * 4) = p;
        }
    }
    __syncthreads();

    // ---------------- Phase 2: K=512, 16 k-steps; wave owns 64 out-rows ----------------
    f32x4 o[4][4];
#pragma unroll
    for (int mi = 0; mi < 4; mi++)
#pragma unroll
        for (int ni = 0; ni < 4; ni++) o[mi][ni] = (f32x4){0.f,0.f,0.f,0.f};

#pragma unroll
    for (int k = 0; k < 16; k++) {
        bf16x8 a2[4], hb[4];
#pragma unroll
        for (int mi = 0; mi < 4; mi++)
            a2[mi] = *reinterpret_cast<const bf16x8*>(
                afp + (size_t)k * 16384 + mi * 512);
#pragma unroll
        for (int ni = 0; ni < 4; ni++)
            hb[ni] = *reinterpret_cast<const bf16x8*>(
                ht + ((k * 4 + ni) * 64 + lane) * 8);
#pragma unroll
        for (int mi = 0; mi < 4; mi++)
#pragma unroll
            for (int ni = 0; ni < 4; ni++)
                o[mi][ni] = __builtin_amdgcn_mfma_f32_16x16x32_bf16(
                    a2[mi], hb[ni], o[mi][ni], 0, 0, 0);
    }

    // Store out fp32: row i = wave*64 + mi*16 + quad*4 + r, col dq*64 + ni*16 + l15
    float* ob = out + ((size_t)b * 512) * 256 + dq * 64;
#pragma unroll
    for (int mi = 0; mi < 4; mi++) {
        int i0 = wave * 64 + mi * 16 + quad * 4;
#pragma unroll
        for (int ni = 0; ni < 4; ni++) {
            int d = ni * 16 + l15;
#pragma unroll
            for (int r = 0; r < 4; r++)
                ob[(size_t)(i0 + r) * 256 + d] = o[mi][ni][r];
        }
    }
}

extern "C" void kernel_launch(void* const* d_in, const int* in_sizes, int n_in,
                              void* d_out, int out_size, void* d_ws, size_t ws_size,
                              hipStream_t stream) {
    const float* x   = (const float*)d_in[0];
    // d_in[1] = batch ids (unused; block-contiguous layout by construction)
    const float* W   = (const float*)d_in[2];
    const float* Adj = (const float*)d_in[3];
    float* out = (float*)d_out;

    unsigned short* xfrag = (unsigned short*)d_ws;    // 8388608 elems (16 MB)
    unsigned short* afrag = xfrag + 8388608;          // 262144 elems (512 KB)
    unsigned short* wfrag = afrag + 262144;           // 65536 elems (128 KB)

    prep<<<4256, 256, 0, stream>>>(x, Adj, W, xfrag, afrag, wfrag);
    fused<<<dim3(64, 4), 512, 0, stream>>>(xfrag, wfrag, afrag, out);
}